// Round 8
// baseline (370.963 us; speedup 1.0000x reference)
//
#include <hip/hip_runtime.h>
#include <hip/hip_cooperative_groups.h>

namespace cg = cooperative_groups;

typedef unsigned short u16;
typedef __attribute__((ext_vector_type(8))) short short8;
typedef __attribute__((ext_vector_type(4))) float f32x4;

#define GLL16(g, l) __builtin_amdgcn_global_load_lds(                         \
    (const __attribute__((address_space(1))) void*)(g),                        \
    (__attribute__((address_space(3))) void*)(l), 16, 0, 0)

__device__ __forceinline__ u16 f2bf(float f) {
  union { float f; unsigned u; } v; v.f = f;
  unsigned u = v.u;
  return (u16)((u + 0x7FFFu + ((u >> 16) & 1u)) >> 16);  // RNE
}

__device__ __forceinline__ ushort4 cvt4(float4 v) {
  ushort4 o; o.x = f2bf(v.x); o.y = f2bf(v.y); o.z = f2bf(v.z); o.w = f2bf(v.w);
  return o;
}

// ---------------------------------------------------------------------------
// Single cooperative kernel. 256 blocks x 512 thr, 128 KB LDS (1 block/CU).
// P1: x->bf16 + fp32 router logits (W_router in LDS) + W_base/A_w/B_w converts
// P2: h partials, split-K=8 (block b -> mtile=b>>3, ks=b&7)
// P3: top-2 softmax gates -> sparse gate-scaled G[8192][64] bf16
// P4: main GEMM 256x256 BK=64, R5 read-ahead 4-phase pipeline, K-tiles 0..31
//     + virtual LoRA K-tile 32 (A=G, B=bmt).
// P (h partials, [8][8192][64] f32) lives in d_out; fully consumed in P3
// before P4 overwrites all of d_out. grid.sync() + threadfence between phases.
// ---------------------------------------------------------------------------
__global__ __launch_bounds__(512, 2) void k_fused(
    const float* __restrict__ x, const float* __restrict__ Wb,
    const float* __restrict__ bias, const float* __restrict__ Wr,
    const float* __restrict__ Aw, const float* __restrict__ Bw,
    u16* __restrict__ xbf, u16* __restrict__ wbf, u16* __restrict__ aabf,
    u16* __restrict__ bmt, float* __restrict__ lgt, u16* __restrict__ G,
    float* __restrict__ P, float* __restrict__ out)
{
  __shared__ __align__(16) char smem[131072];
  cg::grid_group grid = cg::this_grid();

  const int tid = threadIdx.x;
  const int w = tid >> 6, lane = tid & 63;
  const int fr = lane & 15, fg = lane >> 4;
  const int rl = lane >> 3;                 // 0..7
  const int lcol = (lane & 7) * 8;          // linear staging col (elems)
  const int ce = ((lane & 7) ^ rl) << 3;    // swizzled staging col (elems)

  // ===================== Phase 1: converts + router =======================
  {
    float* wlds = (float*)smem;  // 8 x 2048 fp32 = 64 KB
    {
      const float4* src = (const float4*)Wr;
      float4* dst = (float4*)wlds;
#pragma unroll
      for (int i = 0; i < 8; ++i) dst[tid + i * 512] = src[tid + i * 512];
    }
    __syncthreads();
    const float4* wv = (const float4*)wlds;
#pragma unroll 1
    for (int s = 0; s < 4; ++s) {
      int tok = blockIdx.x * 32 + w * 4 + s;
      const float4* xrow = (const float4*)(x + tok * 2048);
      ushort4* orow = (ushort4*)(xbf + tok * 2048);
      float acc[8];
#pragma unroll
      for (int e = 0; e < 8; ++e) acc[e] = 0.f;
#pragma unroll 1
      for (int i = 0; i < 8; ++i) {
        float4 xv = xrow[lane + i * 64];
        orow[lane + i * 64] = cvt4(xv);
#pragma unroll
        for (int e = 0; e < 8; ++e) {
          float4 b = wv[e * 512 + lane + i * 64];
          acc[e] += xv.x * b.x + xv.y * b.y + xv.z * b.z + xv.w * b.w;
        }
      }
#pragma unroll
      for (int e = 0; e < 8; ++e) {
        float v = acc[e];
#pragma unroll
        for (int off = 32; off > 0; off >>= 1) v += __shfl_xor(v, off, 64);
        acc[e] = v;
      }
      if (lane == 0) {
#pragma unroll
        for (int e = 0; e < 8; ++e) lgt[tok * 8 + e] = acc[e];
      }
    }
    // weight conversions (131072 threads grid-wide)
    const int tidg = blockIdx.x * 512 + tid;
    {
      const float4* src = (const float4*)Wb;   // 1,048,576 float4
      ushort4* dst = (ushort4*)wbf;
#pragma unroll
      for (int i = 0; i < 8; ++i) {
        dst[tidg + i * 131072] = cvt4(src[tidg + i * 131072]);
      }
    }
    if (tidg < 32768) {                        // A_w: 32768 float4
      ((ushort4*)aabf)[tidg] = cvt4(((const float4*)Aw)[tidg]);
    }
    if (tidg < 2048) {                         // B_w -> bmt [2048][64]
      const int n = tidg;
#pragma unroll
      for (int e = 0; e < 8; ++e) {
        const float4* src = (const float4*)(Bw + e * 16384 + n * 8);
        ushort4* dst = (ushort4*)(bmt + n * 64 + e * 8);
        dst[0] = cvt4(src[0]);
        dst[1] = cvt4(src[1]);
      }
    }
  }
  __threadfence();
  grid.sync();

  // ===================== Phase 2: h partials (split-K) ====================
  {
    u16* As = (u16*)smem;             // 256*64 u16 = 32 KB
    u16* Bs = (u16*)(smem + 32768);   //  64*64 u16 =  8 KB
    const int mBase = (blockIdx.x >> 3) * 256;
    const int ks = blockIdx.x & 7;
    f32x4 acc[2][4];
    const f32x4 zero = {0.f, 0.f, 0.f, 0.f};
#pragma unroll
    for (int i = 0; i < 2; ++i)
#pragma unroll
      for (int j = 0; j < 4; ++j) acc[i][j] = zero;
#pragma unroll 1
    for (int it = 0; it < 4; ++it) {
      const int k0 = ks * 256 + it * 64;
      __syncthreads();
#pragma unroll
      for (int cc = 0; cc < 4; ++cc) {
        const int c = w * 4 + cc;
        GLL16(xbf + (mBase + c * 8 + rl) * 2048 + k0 + lcol, As + c * 512);
      }
      GLL16(aabf + (w * 8 + rl) * 2048 + k0 + lcol, Bs + w * 512);
      __syncthreads();
#pragma unroll
      for (int kk = 0; kk < 2; ++kk) {
        short8 a[2], bfr[4];
#pragma unroll
        for (int i = 0; i < 2; ++i)
          a[i] = *(const short8*)&As[(w * 32 + i * 16 + fr) * 64 + kk * 32 + fg * 8];
#pragma unroll
        for (int j = 0; j < 4; ++j)
          bfr[j] = *(const short8*)&Bs[(j * 16 + fr) * 64 + kk * 32 + fg * 8];
#pragma unroll
        for (int i = 0; i < 2; ++i)
#pragma unroll
          for (int j = 0; j < 4; ++j)
            acc[i][j] = __builtin_amdgcn_mfma_f32_16x16x32_bf16(a[i], bfr[j], acc[i][j], 0, 0, 0);
      }
    }
#pragma unroll
    for (int i = 0; i < 2; ++i)
#pragma unroll
      for (int j = 0; j < 4; ++j)
#pragma unroll
        for (int r = 0; r < 4; ++r) {
          const int m = mBase + w * 32 + i * 16 + fg * 4 + r;
          const int n = j * 16 + fr;
          P[(ks * 8192 + m) * 64 + n] = acc[i][j][r];
        }
  }
  __threadfence();
  grid.sync();

  // ===================== Phase 3: top-2 gates -> G ========================
  {
#pragma unroll 1
    for (int s = 0; s < 4; ++s) {
      const int tok = blockIdx.x * 32 + w * 4 + s;
      const float* lg = lgt + tok * 8;
      float la[8];
#pragma unroll
      for (int e = 0; e < 8; ++e) la[e] = lg[e];
      float v0 = la[0]; int i0 = 0;
#pragma unroll
      for (int e = 1; e < 8; ++e) { if (la[e] > v0) { v0 = la[e]; i0 = e; } }
      float v1 = -3.4e38f; int i1 = 0;
#pragma unroll
      for (int e = 0; e < 8; ++e) { if (e != i0 && la[e] > v1) { v1 = la[e]; i1 = e; } }
      const float ex = expf(v1 - v0);
      const float inv = 1.f / (1.f + ex);
      const float gate0 = inv, gate1 = ex * inv;
      const int e = lane >> 3;
      float h = 0.f;
#pragma unroll
      for (int ks = 0; ks < 8; ++ks) h += P[(ks * 8192 + tok) * 64 + lane];
      const float g = (e == i0) ? gate0 : ((e == i1) ? gate1 : 0.f);
      G[tok * 64 + lane] = f2bf(2.0f * g * h);  // SCALE = alpha/r = 2
    }
  }
  __threadfence();
  grid.sync();

  // ===================== Phase 4: main GEMM (R5 body) =====================
  {
    u16* ldsb = (u16*)smem;  // A bufs: [0,32768)  B bufs: [32768,65536) u16
    const int wr = w >> 2, wc = w & 3;

    // XCD-aware swizzle (256 blocks, 256%8==0 -> bijective)
    const int b0 = blockIdx.x;
    const int wg = (b0 & 7) * 32 + (b0 >> 3);
    const int mBase = (wg >> 3) * 256;
    const int nBase = (wg & 7) * 256;

    const int swz = (fr & 7) << 3;
    const int colk0 = (fg * 8) ^ swz;
    const int colk1 = (32 + fg * 8) ^ swz;
    const int aOff = (wr * 128 + fr) * 64;
    const int bOff = (wc * 64 + fr) * 64;

    f32x4 acc[8][4];
    const f32x4 zero = {0.f, 0.f, 0.f, 0.f};
#pragma unroll
    for (int mi = 0; mi < 8; ++mi)
#pragma unroll
      for (int nj = 0; nj < 4; ++nj) acc[mi][nj] = zero;

    // half codes: 0=A.lo 1=A.hi 2=B.lo 3=B.hi
    auto STAGE = [&](int s, int which) {
      if (s > 32) return;
      const bool isA = (which < 2);
      const int h = which & 1;
      const u16* src; int ld, k0;
      if (s < 32) { src = isA ? xbf : wbf; ld = 2048; k0 = s * 64; }
      else        { src = isA ? G   : bmt; ld = 64;   k0 = 0;      }
      const int rb = (isA ? mBase : nBase) + h * 128 + w * 8 + rl;
      u16* dst = ldsb + (isA ? 0 : 32768) + (s & 1) * 16384 + h * 8192 + w * 512;
      GLL16(src + rb * ld + k0 + ce, dst);
      GLL16(src + (rb + 64) * ld + k0 + ce, dst + 4096);
    };

    short8 Aa[2][2], Ab[2][2];   // A mi-pair ping-pong
    short8 Bx[4][2], By[4][2];   // B tile ping-pong (full tile in regs)

#define LGKM(N) asm volatile("s_waitcnt lgkmcnt(" #N ")" ::: "memory")
#define VMC(N)  asm volatile("s_waitcnt vmcnt(" #N ")" ::: "memory")
#define BAR()   __builtin_amdgcn_s_barrier()

#define RDA(DST, BUF, MI0)                                                    \
  DST[0][0] = *(const short8*)((BUF) + aOff + (MI0) * 1024 + colk0);          \
  DST[0][1] = *(const short8*)((BUF) + aOff + (MI0) * 1024 + colk1);          \
  DST[1][0] = *(const short8*)((BUF) + aOff + ((MI0) + 1) * 1024 + colk0);    \
  DST[1][1] = *(const short8*)((BUF) + aOff + ((MI0) + 1) * 1024 + colk1);

#define RDB(DST, BUF, NJ0)                                                    \
  DST[(NJ0)][0] = *(const short8*)((BUF) + bOff + (NJ0) * 1024 + colk0);      \
  DST[(NJ0)][1] = *(const short8*)((BUF) + bOff + (NJ0) * 1024 + colk1);      \
  DST[(NJ0)+1][0] = *(const short8*)((BUF) + bOff + ((NJ0)+1) * 1024 + colk0);\
  DST[(NJ0)+1][1] = *(const short8*)((BUF) + bOff + ((NJ0)+1) * 1024 + colk1);

#define MFMA16(AV, BV, MI0)                                                   \
  __builtin_amdgcn_s_setprio(1);                                              \
  _Pragma("unroll")                                                           \
  for (int kk = 0; kk < 2; ++kk)                                              \
    _Pragma("unroll")                                                         \
    for (int q = 0; q < 2; ++q)                                               \
      _Pragma("unroll")                                                       \
      for (int nj = 0; nj < 4; ++nj)                                          \
        acc[(MI0) + q][nj] = __builtin_amdgcn_mfma_f32_16x16x32_bf16(         \
            AV[q][kk], BV[nj][kk], acc[(MI0) + q][nj], 0, 0, 0);              \
  __builtin_amdgcn_s_setprio(0);

#define TILE(T, Pp, BC, BN)                                                   \
  {                                                                           \
    const u16* Acur = ldsb + (Pp) * 16384;                                    \
    const u16* Anxt = ldsb + (1 - (Pp)) * 16384;                              \
    const u16* Bnxt = ldsb + 32768 + (1 - (Pp)) * 16384;                      \
    /* p0 */                                                                  \
    STAGE((T) + 1, 0);                                                        \
    RDA(Ab, Acur, 2)                                                          \
    LGKM(4);                                                                  \
    MFMA16(Aa, BC, 0)                                                         \
    BAR();                                                                    \
    /* p1 */                                                                  \
    STAGE((T) + 1, 1);                                                        \
    RDA(Aa, Acur, 4)                                                          \
    LGKM(4);                                                                  \
    MFMA16(Ab, BC, 2)                                                         \
    VMC(4);                                                                   \
    BAR();                                                                    \
    /* p2 */                                                                  \
    STAGE((T) + 2, 2);                                                        \
    RDA(Ab, Acur, 6)                                                          \
    RDB(BN, Bnxt, 0)                                                          \
    LGKM(8);                                                                  \
    MFMA16(Aa, BC, 4)                                                         \
    if ((T) == 31) { VMC(0); } else { VMC(2); }                               \
    BAR();                                                                    \
    /* p3 */                                                                  \
    STAGE((T) + 2, 3);                                                        \
    RDA(Aa, Anxt, 0)                                                          \
    RDB(BN, Bnxt, 2)                                                          \
    LGKM(8);                                                                  \
    MFMA16(Ab, BC, 6)                                                         \
    BAR();                                                                    \
  }

    // prologue: stage A0,B0,B1 (12 loads); land A0,B0; read B0 + A01(0)
    STAGE(0, 0); STAGE(0, 1); STAGE(0, 2); STAGE(0, 3);
    STAGE(1, 2); STAGE(1, 3);
    VMC(4);
    BAR();
    {
      const u16* Bb0 = ldsb + 32768;
      RDB(Bx, Bb0, 0)
      RDB(Bx, Bb0, 2)
      RDA(Aa, ldsb, 0)
    }

#pragma unroll 1
    for (int tt = 0; tt < 16; ++tt) {
      const int t0 = tt * 2;
      TILE(t0, 0, Bx, By)
      TILE(t0 + 1, 1, By, Bx)
    }

    // tile 32 (LoRA): no stages, no barriers, Bcur = Bx
    {
      const u16* Acur = ldsb;  // 32&1 == 0
      RDA(Ab, Acur, 2)
      LGKM(4);
      MFMA16(Aa, Bx, 0)
      RDA(Aa, Acur, 4)
      LGKM(4);
      MFMA16(Ab, Bx, 2)
      RDA(Ab, Acur, 6)
      LGKM(4);
      MFMA16(Aa, Bx, 4)
      LGKM(0);
      MFMA16(Ab, Bx, 6)
    }

    // epilogue: bias add + store
#pragma unroll
    for (int nj = 0; nj < 4; ++nj) {
      const int n = nBase + wc * 64 + nj * 16 + fr;
      const float bv = bias[n];
#pragma unroll
      for (int mi = 0; mi < 8; ++mi) {
        const int m = mBase + wr * 128 + mi * 16 + fg * 4;
#pragma unroll
        for (int r = 0; r < 4; ++r)
          out[(m + r) * 2048 + n] = acc[mi][nj][r] + bv;
      }
    }
#undef TILE
#undef MFMA16
#undef RDB
#undef RDA
#undef BAR
#undef VMC
#undef LGKM
  }
}

// ---------------------------------------------------------------------------
extern "C" void kernel_launch(void* const* d_in, const int* in_sizes, int n_in,
                              void* d_out, int out_size, void* d_ws, size_t ws_size,
                              hipStream_t stream) {
  const float* x  = (const float*)d_in[0];   // [4,2048,2048]
  const float* Wb = (const float*)d_in[1];   // [2048,2048]
  const float* bb = (const float*)d_in[2];   // [2048]
  const float* Wr = (const float*)d_in[3];   // [8,2048]
  const float* Aw = (const float*)d_in[4];   // [8,8,2048] == [64][2048]
  const float* Bw = (const float*)d_in[5];   // [8,2048,8]

  char* ws = (char*)d_ws;
  u16*   xbf  = (u16*)  (ws + 0);            // 33,554,432 B
  u16*   wbf  = (u16*)  (ws + 33554432);     //  8,388,608 B
  u16*   aabf = (u16*)  (ws + 41943040);     //    262,144 B
  u16*   bmt  = (u16*)  (ws + 42205184);     //    262,144 B
  float* lgt  = (float*)(ws + 42467328);     //    262,144 B
  u16*   G    = (u16*)  (ws + 42729472);     //  1,048,576 B
  // h-partials [8][8192][64] f32 live in d_out; fully consumed in phase 3
  // before phase 4 overwrites all of d_out (single kernel, grid-fenced).
  float* P   = (float*)d_out;
  float* out = (float*)d_out;

  void* args[] = { (void*)&x, (void*)&Wb, (void*)&bb, (void*)&Wr,
                   (void*)&Aw, (void*)&Bw,
                   (void*)&xbf, (void*)&wbf, (void*)&aabf, (void*)&bmt,
                   (void*)&lgt, (void*)&G, (void*)&P, (void*)&out };
  hipLaunchCooperativeKernel((const void*)k_fused, dim3(256), dim3(512),
                             args, 0, stream);
}

// Round 9
// 145.493 us; speedup vs baseline: 2.5497x; 2.5497x over previous
//
#include <hip/hip_runtime.h>

typedef unsigned short u16;
typedef __attribute__((ext_vector_type(8))) short short8;
typedef __attribute__((ext_vector_type(4))) float f32x4;

#define GLL16(g, l) __builtin_amdgcn_global_load_lds(                         \
    (const __attribute__((address_space(1))) void*)(g),                        \
    (__attribute__((address_space(3))) void*)(l), 16, 0, 0)

__device__ __forceinline__ u16 f2bf(float f) {
  union { float f; unsigned u; } v; v.f = f;
  unsigned u = v.u;
  return (u16)((u + 0x7FFFu + ((u >> 16) & 1u)) >> 16);  // RNE
}

// ---------------------------------------------------------------------------
// Kernel A: convert x -> bf16, compute fp32 router logits (W_router in LDS).
// ---------------------------------------------------------------------------
__global__ __launch_bounds__(512) void k_conv_router(
    const float* __restrict__ x, const float* __restrict__ Wr,
    u16* __restrict__ xbf, float* __restrict__ logits)
{
  __shared__ float wlds[16384];  // 8 x 2048 fp32 = 64 KB
  {
    const float4* src = (const float4*)Wr;
    float4* dst = (float4*)wlds;
    int t = threadIdx.x;
#pragma unroll
    for (int i = 0; i < 8; ++i) dst[t + i * 512] = src[t + i * 512];
  }
  __syncthreads();
  int wave = threadIdx.x >> 6, lane = threadIdx.x & 63;
  const float4* wv = (const float4*)wlds;
#pragma unroll 1
  for (int s = 0; s < 2; ++s) {
    int tok = blockIdx.x * 16 + wave * 2 + s;
    const float4* xrow = (const float4*)(x + tok * 2048);
    ushort4* orow = (ushort4*)(xbf + tok * 2048);
    float acc[8];
#pragma unroll
    for (int e = 0; e < 8; ++e) acc[e] = 0.f;
#pragma unroll 1
    for (int i = 0; i < 8; ++i) {
      float4 xv = xrow[lane + i * 64];
      ushort4 o;
      o.x = f2bf(xv.x); o.y = f2bf(xv.y);
      o.z = f2bf(xv.z); o.w = f2bf(xv.w);
      orow[lane + i * 64] = o;
#pragma unroll
      for (int e = 0; e < 8; ++e) {
        float4 b = wv[e * 512 + lane + i * 64];
        acc[e] += xv.x * b.x + xv.y * b.y + xv.z * b.z + xv.w * b.w;
      }
    }
#pragma unroll
    for (int e = 0; e < 8; ++e) {
      float v = acc[e];
#pragma unroll
      for (int off = 32; off > 0; off >>= 1) v += __shfl_xor(v, off, 64);
      acc[e] = v;
    }
    if (lane == 0) {
#pragma unroll
      for (int e = 0; e < 8; ++e) logits[tok * 8 + e] = acc[e];
    }
  }
}

// ---------------------------------------------------------------------------
// Kernel B: W_base->bf16, A_w->bf16, B_w -> BmatT [2048][64] bf16.
// ---------------------------------------------------------------------------
__global__ __launch_bounds__(256) void k_convert(
    const float* __restrict__ Wb, const float* __restrict__ Aw,
    const float* __restrict__ Bw,
    u16* __restrict__ wbf, u16* __restrict__ aabf, u16* __restrict__ bmt)
{
  int b = blockIdx.x, t = threadIdx.x;
  if (b < 1024) {
    int tid = b * 256 + t;
    const float4* src = (const float4*)Wb;
    ushort4* dst = (ushort4*)wbf;
#pragma unroll
    for (int i = 0; i < 4; ++i) {
      float4 v = src[tid + i * 262144];
      ushort4 o; o.x = f2bf(v.x); o.y = f2bf(v.y); o.z = f2bf(v.z); o.w = f2bf(v.w);
      dst[tid + i * 262144] = o;
    }
  } else if (b < 1056) {
    int tid = (b - 1024) * 256 + t;
    const float4* src = (const float4*)Aw;
    ushort4* dst = (ushort4*)aabf;
#pragma unroll
    for (int i = 0; i < 4; ++i) {
      float4 v = src[tid + i * 8192];
      ushort4 o; o.x = f2bf(v.x); o.y = f2bf(v.y); o.z = f2bf(v.z); o.w = f2bf(v.w);
      dst[tid + i * 8192] = o;
    }
  } else {
    int n = (b - 1056) * 256 + t;  // 0..2047
#pragma unroll
    for (int e = 0; e < 8; ++e) {
      const float4* src = (const float4*)(Bw + e * 16384 + n * 8);
      float4 v0 = src[0], v1 = src[1];
      ushort4 o0, o1;
      o0.x = f2bf(v0.x); o0.y = f2bf(v0.y); o0.z = f2bf(v0.z); o0.w = f2bf(v0.w);
      o1.x = f2bf(v1.x); o1.y = f2bf(v1.y); o1.z = f2bf(v1.z); o1.w = f2bf(v1.w);
      ushort4* dst = (ushort4*)(bmt + n * 64 + e * 8);
      dst[0] = o0; dst[1] = o1;
    }
  }
}

// ---------------------------------------------------------------------------
// Kernel C: h partials. h_all[m][64] = x_bf16 @ A_all^T, split-K (8 slices).
// ---------------------------------------------------------------------------
__global__ __launch_bounds__(256) void k_hgemm(
    const u16* __restrict__ xbf, const u16* __restrict__ aabf,
    float* __restrict__ P)
{
  __shared__ u16 As[256 * 64];
  __shared__ u16 Bs[64 * 64];
  int t = threadIdx.x, wave = t >> 6, lane = t & 63;
  int mBase = blockIdx.x * 256;
  int ks = blockIdx.y;
  int fr = lane & 15, fg = lane >> 4;
  int lrow = lane >> 3, lcol = (lane & 7) * 8;
  f32x4 zero = {0.f, 0.f, 0.f, 0.f};
  f32x4 acc[4][4];
#pragma unroll
  for (int i = 0; i < 4; ++i)
#pragma unroll
    for (int j = 0; j < 4; ++j) acc[i][j] = zero;
#pragma unroll 1
  for (int it = 0; it < 4; ++it) {
    int k0 = ks * 256 + it * 64;
    __syncthreads();
#pragma unroll
    for (int cc = 0; cc < 8; ++cc) {
      int c = wave * 8 + cc;
      GLL16(xbf + (mBase + c * 8 + lrow) * 2048 + k0 + lcol, &As[c * 512]);
    }
#pragma unroll
    for (int cc = 0; cc < 2; ++cc) {
      int c = wave * 2 + cc;
      GLL16(aabf + (c * 8 + lrow) * 2048 + k0 + lcol, &Bs[c * 512]);
    }
    __syncthreads();
#pragma unroll
    for (int kk = 0; kk < 2; ++kk) {
      short8 a[4], bfr[4];
#pragma unroll
      for (int i = 0; i < 4; ++i)
        a[i] = *(const short8*)&As[(wave * 64 + i * 16 + fr) * 64 + kk * 32 + fg * 8];
#pragma unroll
      for (int j = 0; j < 4; ++j)
        bfr[j] = *(const short8*)&Bs[(j * 16 + fr) * 64 + kk * 32 + fg * 8];
#pragma unroll
      for (int i = 0; i < 4; ++i)
#pragma unroll
        for (int j = 0; j < 4; ++j)
          acc[i][j] = __builtin_amdgcn_mfma_f32_16x16x32_bf16(a[i], bfr[j], acc[i][j], 0, 0, 0);
    }
  }
#pragma unroll
  for (int i = 0; i < 4; ++i)
#pragma unroll
    for (int j = 0; j < 4; ++j)
#pragma unroll
      for (int r = 0; r < 4; ++r) {
        int m = mBase + wave * 64 + i * 16 + fg * 4 + r;
        int n = j * 16 + fr;
        P[(ks * 8192 + m) * 64 + n] = acc[i][j][r];
      }
}

// ---------------------------------------------------------------------------
// Kernel D: per-token top-2 + softmax gates; reduce split-K partials; emit
// sparse gate-scaled G[8192][64] bf16.
// ---------------------------------------------------------------------------
__global__ __launch_bounds__(256) void k_topk(
    const float* __restrict__ logits, const float* __restrict__ P,
    u16* __restrict__ G)
{
  int t = threadIdx.x, wave = t >> 6, lane = t & 63;
  int tok = blockIdx.x * 4 + wave;
  const float* lg = logits + tok * 8;
  float la[8];
#pragma unroll
  for (int e = 0; e < 8; ++e) la[e] = lg[e];
  float v0 = la[0]; int i0 = 0;
#pragma unroll
  for (int e = 1; e < 8; ++e) { if (la[e] > v0) { v0 = la[e]; i0 = e; } }
  float v1 = -3.4e38f; int i1 = 0;
#pragma unroll
  for (int e = 0; e < 8; ++e) { if (e != i0 && la[e] > v1) { v1 = la[e]; i1 = e; } }
  float ex = expf(v1 - v0);
  float inv = 1.f / (1.f + ex);
  float gate0 = inv, gate1 = ex * inv;
  int e = lane >> 3;
  float h = 0.f;
#pragma unroll
  for (int ks = 0; ks < 8; ++ks) h += P[(ks * 8192 + tok) * 64 + lane];
  float g = (e == i0) ? gate0 : ((e == i1) ? gate1 : 0.f);
  G[tok * 64 + lane] = f2bf(2.0f * g * h);  // SCALE = alpha/r = 2
}

// ---------------------------------------------------------------------------
// Kernel E: main GEMM, 256x256, BK=64. B-OPERAND FROM GLOBAL (L2), A via LDS.
// K = 2048 (tiles 0..31) + virtual LoRA K-tile 32 (A=G, B=BmT, ld=64).
// LDS = A only, 2 x 32KB double buffer (64KB). Per tile: 128 ds_read_b128
// (~1540cyc/CU) < MFMA floor (~2484cyc) -> MFMA-bound if overlapped.
// XCD map: nTile = b0&7 (per-XCD W panel = 1MB, L2-resident), mTile = b0>>3.
// Per tile t (2 barriers, 2 vmcnt, 4 lgkm):
//   p0: STAGE A(t+1).lo | RDA Ab<-mi23 | LGKM(4) | VMC(2) [retire B(t) 8 gld]
//       | MFMA mi01
//   p1: STAGE A(t+1).hi | RDA Aa<-mi45 | LGKM(4) | MFMA mi23
//   p2: gld B(t+1) nj01 | RDA Ab<-mi67 | LGKM(4) | MFMA mi45
//       | VMC(4) [retire A(t+1) gll; keep B(t+1) 4] | BAR
//   p3: gld B(t+1) nj23 | RDA Aa<-A(t+1) mi01 | LGKM(4) | MFMA mi67 | BAR
// Read-before-overwrite: wave's last A(t) read (p2) retired by p3's LGKM(4);
// p3-end BAR fences next tile's A(t+2) staging. Stage-before-read: A(t+1)
// retired at p2's VMC(4) + p2-end BAR before p3's RDA(Anxt). B regs private.
// ---------------------------------------------------------------------------
__global__ __launch_bounds__(512, 2) void k_main(
    const u16* __restrict__ xbf, const u16* __restrict__ wbf,
    const u16* __restrict__ G, const u16* __restrict__ BmT,
    const float* __restrict__ bias, float* __restrict__ out)
{
  __shared__ u16 lds[32768];  // A double buffer: 2 x 16384 u16 (64 KB)
  const int tid = threadIdx.x;
  const int w = tid >> 6, lane = tid & 63;
  const int fr = lane & 15, fg = lane >> 4;
  const int wr = w >> 2, wc = w & 3;

  // XCD map: n-panel per XCD (W slice 1MB -> L2-resident)
  const int b0 = blockIdx.x;
  const int mBase = (b0 >> 3) * 256;   // 32 m-tiles
  const int nBase = (b0 & 7) * 256;    //  8 n-tiles (= XCD id)

  // A staging (linear LDS dest; swizzled global source col)
  const int rl = lane >> 3;                 // 0..7
  const int ce = ((lane & 7) ^ rl) << 3;    // source col elems (XOR swizzle)
  // A ds_read addressing (same XOR involution)
  const int swz = (fr & 7) << 3;
  const int colk0 = (fg * 8) ^ swz;
  const int colk1 = (32 + fg * 8) ^ swz;
  const int aOff = (wr * 128 + fr) * 64;
  // B global row base
  const int bRow = nBase + wc * 64 + fr;

  f32x4 acc[8][4];
  const f32x4 zero = {0.f, 0.f, 0.f, 0.f};
#pragma unroll
  for (int mi = 0; mi < 8; ++mi)
#pragma unroll
    for (int nj = 0; nj < 4; ++nj) acc[mi][nj] = zero;

  // A half codes: 0=lo 1=hi
  auto STAGE = [&](int s, int h) {
    if (s > 32) return;
    const u16* src; int ld, k0;
    if (s < 32) { src = xbf; ld = 2048; k0 = s * 64; }
    else        { src = G;   ld = 64;   k0 = 0;      }
    const int rb = mBase + h * 128 + w * 8 + rl;
    u16* dst = lds + (s & 1) * 16384 + h * 8192 + w * 512;
    GLL16(src + rb * ld + k0 + ce, dst);                // rows rb..    (q=0)
    GLL16(src + (rb + 64) * ld + k0 + ce, dst + 4096);  // rows rb+64.. (q=1)
  };

  short8 Aa[2][2], Ab[2][2];   // A mi-pair ping-pong (LDS-sourced)
  short8 Bx[4][2], By[4][2];   // B tile ping-pong (global-sourced regs)

#define LGKM(N) asm volatile("s_waitcnt lgkmcnt(" #N ")" ::: "memory")
#define VMC(N)  asm volatile("s_waitcnt vmcnt(" #N ")" ::: "memory")
#define BAR()   __builtin_amdgcn_s_barrier()

#define RDA(DST, BUF, MI0)                                                    \
  DST[0][0] = *(const short8*)((BUF) + aOff + (MI0) * 1024 + colk0);          \
  DST[0][1] = *(const short8*)((BUF) + aOff + (MI0) * 1024 + colk1);          \
  DST[1][0] = *(const short8*)((BUF) + aOff + ((MI0) + 1) * 1024 + colk0);    \
  DST[1][1] = *(const short8*)((BUF) + aOff + ((MI0) + 1) * 1024 + colk1);

  // 4 global 16B loads: B rows (bRow + {NJ0,NJ0+1}*16), k = K0 + kk*32 + fg*8
#define RDBG(DST, SRC, LD, K0, NJ0)                                           \
  DST[(NJ0)][0] = *(const short8*)((SRC) + (bRow + (NJ0) * 16) * (LD) +       \
                                   (K0) + fg * 8);                            \
  DST[(NJ0)][1] = *(const short8*)((SRC) + (bRow + (NJ0) * 16) * (LD) +       \
                                   (K0) + 32 + fg * 8);                       \
  DST[(NJ0) + 1][0] = *(const short8*)((SRC) + (bRow + ((NJ0) + 1) * 16) *    \
                                       (LD) + (K0) + fg * 8);                 \
  DST[(NJ0) + 1][1] = *(const short8*)((SRC) + (bRow + ((NJ0) + 1) * 16) *    \
                                       (LD) + (K0) + 32 + fg * 8);

#define MFMA16(AV, BV, MI0)                                                   \
  __builtin_amdgcn_s_setprio(1);                                              \
  _Pragma("unroll")                                                           \
  for (int kk = 0; kk < 2; ++kk)                                              \
    _Pragma("unroll")                                                         \
    for (int q = 0; q < 2; ++q)                                               \
      _Pragma("unroll")                                                       \
      for (int nj = 0; nj < 4; ++nj)                                          \
        acc[(MI0) + q][nj] = __builtin_amdgcn_mfma_f32_16x16x32_bf16(         \
            AV[q][kk], BV[nj][kk], acc[(MI0) + q][nj], 0, 0, 0);              \
  __builtin_amdgcn_s_setprio(0);

  // TILE(T, P=T&1, BC=cur B regs, BN=next B regs)
#define TILE(T, P, BC, BN)                                                    \
  {                                                                           \
    const u16* Acur = lds + (P) * 16384;                                      \
    const u16* Anxt = lds + (1 - (P)) * 16384;                                \
    const u16* bns = ((T) + 1 < 32) ? wbf : BmT;                              \
    const int bld = ((T) + 1 < 32) ? 2048 : 64;                               \
    const int bk0 = ((T) + 1 < 32) ? ((T) + 1) * 64 : 0;                      \
    /* p0 */                                                                  \
    STAGE((T) + 1, 0);                                                        \
    RDA(Ab, Acur, 2)                                                          \
    LGKM(4);                                                                  \
    VMC(2);                                                                   \
    MFMA16(Aa, BC, 0)                                                         \
    /* p1 */                                                                  \
    STAGE((T) + 1, 1);                                                        \
    RDA(Aa, Acur, 4)                                                          \
    LGKM(4);                                                                  \
    MFMA16(Ab, BC, 2)                                                         \
    /* p2 */                                                                  \
    RDBG(BN, bns, bld, bk0, 0)                                                \
    RDA(Ab, Acur, 6)                                                          \
    LGKM(4);                                                                  \
    MFMA16(Aa, BC, 4)                                                         \
    VMC(4);                                                                   \
    BAR();                                                                    \
    /* p3 */                                                                  \
    RDBG(BN, bns, bld, bk0, 2)                                                \
    RDA(Aa, Anxt, 0)                                                          \
    LGKM(4);                                                                  \
    MFMA16(Ab, BC, 6)                                                         \
    BAR();                                                                    \
  }

  // ---- prologue: stage A(0) (4 gll); load B(0) into regs (8 gld)
  STAGE(0, 0); STAGE(0, 1);
  RDBG(Bx, wbf, 2048, 0, 0)
  RDBG(Bx, wbf, 2048, 0, 2)
  VMC(8);   // retire A(0)'s 4 gll; B(0)'s 8 gld stay in flight
  BAR();
  RDA(Aa, lds, 0)

#pragma unroll 1
  for (int tt = 0; tt < 16; ++tt) {
    const int t0 = tt * 2;
    TILE(t0, 0, Bx, By)
    TILE(t0 + 1, 1, By, Bx)
  }

  // ---- tile 32 (LoRA): A(32) staged at t=31 p0/p1 (parity 0); B(32) in Bx
  {
    const u16* Acur = lds;  // 32&1 == 0
    RDA(Ab, Acur, 2)
    LGKM(4);
    VMC(0);
    MFMA16(Aa, Bx, 0)
    RDA(Aa, Acur, 4)
    LGKM(4);
    MFMA16(Ab, Bx, 2)
    RDA(Ab, Acur, 6)
    LGKM(4);
    MFMA16(Aa, Bx, 4)
    LGKM(0);
    MFMA16(Ab, Bx, 6)
  }

  // ---- epilogue: bias add + store
#pragma unroll
  for (int nj = 0; nj < 4; ++nj) {
    const int n = nBase + wc * 64 + nj * 16 + fr;
    const float bv = bias[n];
#pragma unroll
    for (int mi = 0; mi < 8; ++mi) {
      const int m = mBase + wr * 128 + mi * 16 + fg * 4;
#pragma unroll
      for (int r = 0; r < 4; ++r)
        out[(m + r) * 2048 + n] = acc[mi][nj][r] + bv;
    }
  }
#undef TILE
#undef MFMA16
#undef RDBG
#undef RDA
#undef BAR
#undef VMC
#undef LGKM
}

// ---------------------------------------------------------------------------
extern "C" void kernel_launch(void* const* d_in, const int* in_sizes, int n_in,
                              void* d_out, int out_size, void* d_ws, size_t ws_size,
                              hipStream_t stream) {
  const float* x  = (const float*)d_in[0];   // [4,2048,2048]
  const float* Wb = (const float*)d_in[1];   // [2048,2048]
  const float* bb = (const float*)d_in[2];   // [2048]
  const float* Wr = (const float*)d_in[3];   // [8,2048]
  const float* Aw = (const float*)d_in[4];   // [8,8,2048] == [64][2048]
  const float* Bw = (const float*)d_in[5];   // [8,2048,8]

  char* ws = (char*)d_ws;
  u16*   xbf  = (u16*)  (ws + 0);            // 33,554,432 B
  u16*   wbf  = (u16*)  (ws + 33554432);     //  8,388,608 B
  u16*   aabf = (u16*)  (ws + 41943040);     //    262,144 B
  u16*   bmt  = (u16*)  (ws + 42205184);     //    262,144 B
  float* lgt  = (float*)(ws + 42467328);     //    262,144 B
  u16*   G    = (u16*)  (ws + 42729472);     //  1,048,576 B
  // h-partials [8][8192][64] f32 live in d_out; fully consumed by k_topk
  // before k_main overwrites all of d_out. Same-stream ordering.
  float* P   = (float*)d_out;
  float* out = (float*)d_out;

  hipLaunchKernelGGL(k_conv_router, dim3(512),   dim3(512), 0, stream, x, Wr, xbf, lgt);
  hipLaunchKernelGGL(k_convert,     dim3(1064),  dim3(256), 0, stream, Wb, Aw, Bw, wbf, aabf, bmt);
  hipLaunchKernelGGL(k_hgemm,       dim3(32, 8), dim3(256), 0, stream, xbf, aabf, P);
  hipLaunchKernelGGL(k_topk,        dim3(2048),  dim3(256), 0, stream, lgt, P, G);
  hipLaunchKernelGGL(k_main,        dim3(256),   dim3(512), 0, stream, xbf, wbf, G, bmt, bb, out);
}

// Round 10
// 115.812 us; speedup vs baseline: 3.2032x; 1.2563x over previous
//
#include <hip/hip_runtime.h>

typedef unsigned short u16;
typedef __attribute__((ext_vector_type(8))) short short8;
typedef __attribute__((ext_vector_type(4))) float f32x4;

#define GLL16(g, l) __builtin_amdgcn_global_load_lds(                         \
    (const __attribute__((address_space(1))) void*)(g),                        \
    (__attribute__((address_space(3))) void*)(l), 16, 0, 0)

__device__ __forceinline__ u16 f2bf(float f) {
  union { float f; unsigned u; } v; v.f = f;
  unsigned u = v.u;
  return (u16)((u + 0x7FFFu + ((u >> 16) & 1u)) >> 16);  // RNE
}

// ---------------------------------------------------------------------------
// Kernel A: convert x -> bf16, compute fp32 router logits (W_router in LDS).
// ---------------------------------------------------------------------------
__global__ __launch_bounds__(512) void k_conv_router(
    const float* __restrict__ x, const float* __restrict__ Wr,
    u16* __restrict__ xbf, float* __restrict__ logits)
{
  __shared__ float wlds[16384];  // 8 x 2048 fp32 = 64 KB
  {
    const float4* src = (const float4*)Wr;
    float4* dst = (float4*)wlds;
    int t = threadIdx.x;
#pragma unroll
    for (int i = 0; i < 8; ++i) dst[t + i * 512] = src[t + i * 512];
  }
  __syncthreads();
  int wave = threadIdx.x >> 6, lane = threadIdx.x & 63;
  const float4* wv = (const float4*)wlds;
#pragma unroll 1
  for (int s = 0; s < 2; ++s) {
    int tok = blockIdx.x * 16 + wave * 2 + s;
    const float4* xrow = (const float4*)(x + tok * 2048);
    ushort4* orow = (ushort4*)(xbf + tok * 2048);
    float acc[8];
#pragma unroll
    for (int e = 0; e < 8; ++e) acc[e] = 0.f;
#pragma unroll 1
    for (int i = 0; i < 8; ++i) {
      float4 xv = xrow[lane + i * 64];
      ushort4 o;
      o.x = f2bf(xv.x); o.y = f2bf(xv.y);
      o.z = f2bf(xv.z); o.w = f2bf(xv.w);
      orow[lane + i * 64] = o;
#pragma unroll
      for (int e = 0; e < 8; ++e) {
        float4 b = wv[e * 512 + lane + i * 64];
        acc[e] += xv.x * b.x + xv.y * b.y + xv.z * b.z + xv.w * b.w;
      }
    }
#pragma unroll
    for (int e = 0; e < 8; ++e) {
      float v = acc[e];
#pragma unroll
      for (int off = 32; off > 0; off >>= 1) v += __shfl_xor(v, off, 64);
      acc[e] = v;
    }
    if (lane == 0) {
#pragma unroll
      for (int e = 0; e < 8; ++e) logits[tok * 8 + e] = acc[e];
    }
  }
}

// ---------------------------------------------------------------------------
// Kernel B: W_base->bf16, A_w->bf16, B_w -> BmatT [2048][64] bf16.
// ---------------------------------------------------------------------------
__global__ __launch_bounds__(256) void k_convert(
    const float* __restrict__ Wb, const float* __restrict__ Aw,
    const float* __restrict__ Bw,
    u16* __restrict__ wbf, u16* __restrict__ aabf, u16* __restrict__ bmt)
{
  int b = blockIdx.x, t = threadIdx.x;
  if (b < 1024) {
    int tid = b * 256 + t;
    const float4* src = (const float4*)Wb;
    ushort4* dst = (ushort4*)wbf;
#pragma unroll
    for (int i = 0; i < 4; ++i) {
      float4 v = src[tid + i * 262144];
      ushort4 o; o.x = f2bf(v.x); o.y = f2bf(v.y); o.z = f2bf(v.z); o.w = f2bf(v.w);
      dst[tid + i * 262144] = o;
    }
  } else if (b < 1056) {
    int tid = (b - 1024) * 256 + t;
    const float4* src = (const float4*)Aw;
    ushort4* dst = (ushort4*)aabf;
#pragma unroll
    for (int i = 0; i < 4; ++i) {
      float4 v = src[tid + i * 8192];
      ushort4 o; o.x = f2bf(v.x); o.y = f2bf(v.y); o.z = f2bf(v.z); o.w = f2bf(v.w);
      dst[tid + i * 8192] = o;
    }
  } else {
    int n = (b - 1056) * 256 + t;  // 0..2047
#pragma unroll
    for (int e = 0; e < 8; ++e) {
      const float4* src = (const float4*)(Bw + e * 16384 + n * 8);
      float4 v0 = src[0], v1 = src[1];
      ushort4 o0, o1;
      o0.x = f2bf(v0.x); o0.y = f2bf(v0.y); o0.z = f2bf(v0.z); o0.w = f2bf(v0.w);
      o1.x = f2bf(v1.x); o1.y = f2bf(v1.y); o1.z = f2bf(v1.z); o1.w = f2bf(v1.w);
      ushort4* dst = (ushort4*)(bmt + n * 64 + e * 8);
      dst[0] = o0; dst[1] = o1;
    }
  }
}

// ---------------------------------------------------------------------------
// Kernel C: h partials. h_all[m][64] = x_bf16 @ A_all^T, split-K (8 slices).
// ---------------------------------------------------------------------------
__global__ __launch_bounds__(256) void k_hgemm(
    const u16* __restrict__ xbf, const u16* __restrict__ aabf,
    float* __restrict__ P)
{
  __shared__ u16 As[256 * 64];
  __shared__ u16 Bs[64 * 64];
  int t = threadIdx.x, wave = t >> 6, lane = t & 63;
  int mBase = blockIdx.x * 256;
  int ks = blockIdx.y;
  int fr = lane & 15, fg = lane >> 4;
  int lrow = lane >> 3, lcol = (lane & 7) * 8;
  f32x4 zero = {0.f, 0.f, 0.f, 0.f};
  f32x4 acc[4][4];
#pragma unroll
  for (int i = 0; i < 4; ++i)
#pragma unroll
    for (int j = 0; j < 4; ++j) acc[i][j] = zero;
#pragma unroll 1
  for (int it = 0; it < 4; ++it) {
    int k0 = ks * 256 + it * 64;
    __syncthreads();
#pragma unroll
    for (int cc = 0; cc < 8; ++cc) {
      int c = wave * 8 + cc;
      GLL16(xbf + (mBase + c * 8 + lrow) * 2048 + k0 + lcol, &As[c * 512]);
    }
#pragma unroll
    for (int cc = 0; cc < 2; ++cc) {
      int c = wave * 2 + cc;
      GLL16(aabf + (c * 8 + lrow) * 2048 + k0 + lcol, &Bs[c * 512]);
    }
    __syncthreads();
#pragma unroll
    for (int kk = 0; kk < 2; ++kk) {
      short8 a[4], bfr[4];
#pragma unroll
      for (int i = 0; i < 4; ++i)
        a[i] = *(const short8*)&As[(wave * 64 + i * 16 + fr) * 64 + kk * 32 + fg * 8];
#pragma unroll
      for (int j = 0; j < 4; ++j)
        bfr[j] = *(const short8*)&Bs[(j * 16 + fr) * 64 + kk * 32 + fg * 8];
#pragma unroll
      for (int i = 0; i < 4; ++i)
#pragma unroll
        for (int j = 0; j < 4; ++j)
          acc[i][j] = __builtin_amdgcn_mfma_f32_16x16x32_bf16(a[i], bfr[j], acc[i][j], 0, 0, 0);
    }
  }
#pragma unroll
  for (int i = 0; i < 4; ++i)
#pragma unroll
    for (int j = 0; j < 4; ++j)
#pragma unroll
      for (int r = 0; r < 4; ++r) {
        int m = mBase + wave * 64 + i * 16 + fg * 4 + r;
        int n = j * 16 + fr;
        P[(ks * 8192 + m) * 64 + n] = acc[i][j][r];
      }
}

// ---------------------------------------------------------------------------
// Kernel D: per-token top-2 + softmax gates; reduce split-K partials; emit
// sparse gate-scaled G[8192][64] bf16.
// ---------------------------------------------------------------------------
__global__ __launch_bounds__(256) void k_topk(
    const float* __restrict__ logits, const float* __restrict__ P,
    u16* __restrict__ G)
{
  int t = threadIdx.x, wave = t >> 6, lane = t & 63;
  int tok = blockIdx.x * 4 + wave;
  const float* lg = logits + tok * 8;
  float la[8];
#pragma unroll
  for (int e = 0; e < 8; ++e) la[e] = lg[e];
  float v0 = la[0]; int i0 = 0;
#pragma unroll
  for (int e = 1; e < 8; ++e) { if (la[e] > v0) { v0 = la[e]; i0 = e; } }
  float v1 = -3.4e38f; int i1 = 0;
#pragma unroll
  for (int e = 0; e < 8; ++e) { if (e != i0 && la[e] > v1) { v1 = la[e]; i1 = e; } }
  float ex = expf(v1 - v0);
  float inv = 1.f / (1.f + ex);
  float gate0 = inv, gate1 = ex * inv;
  int e = lane >> 3;
  float h = 0.f;
#pragma unroll
  for (int ks = 0; ks < 8; ++ks) h += P[(ks * 8192 + tok) * 64 + lane];
  float g = (e == i0) ? gate0 : ((e == i1) ? gate1 : 0.f);
  G[tok * 64 + lane] = f2bf(2.0f * g * h);  // SCALE = alpha/r = 2
}

// ---------------------------------------------------------------------------
// Kernel E: main GEMM, 256x256, BK=64, R5 read-ahead 4-phase pipeline with
// ZERO-VALU staging: 4 running per-lane source pointers (+=64/tile), LDS dest
// offsets compile-time per tile parity, tiles 30/31 peeled (LoRA G/BmT stage
// explicit -> no runtime branches in the hot loop).
// Schedule/waits identical to R5 (72.4us, verified):
//   p0: stage A(t+1).lo | rd Ab<-mi23      | LGKM(4) | MFMA mi01 | BAR
//   p1: stage A(t+1).hi | rd Aa<-mi45      | LGKM(4) | MFMA mi23 | VMC(4) BAR
//   p2: stage B(t+2).lo | rd Ab<-mi67,Bn01 | LGKM(8) | MFMA mi45 | VMC(2) BAR
//   p3: stage B(t+2).hi | rd Aa<-A(t+1)mi01,Bn23 | LGKM(8) | MFMA mi67 | BAR
// B(t) lives in regs during tile t (read as Bn at t-1 p2/p3).
// ---------------------------------------------------------------------------
__global__ __launch_bounds__(512, 2) void k_main(
    const u16* __restrict__ xbf, const u16* __restrict__ wbf,
    const u16* __restrict__ G, const u16* __restrict__ BmT,
    const float* __restrict__ bias, float* __restrict__ out)
{
  __shared__ u16 lds[65536];  // A bufs: [0,32768)  B bufs: [32768,65536)
  const int tid = threadIdx.x;
  const int w = tid >> 6, lane = tid & 63;
  const int fr = lane & 15, fg = lane >> 4;
  const int wr = w >> 2, wc = w & 3;

  // XCD-aware swizzle (256 blocks, 256%8==0 -> bijective) [R5 mapping]
  const int b0 = blockIdx.x;
  const int wg = (b0 & 7) * 32 + (b0 >> 3);
  const int mBase = (wg >> 3) * 256;   // 32 m-tiles
  const int nBase = (wg & 7) * 256;    //  8 n-tiles

  // staging addressing (linear LDS dest; swizzled global source col)
  const int rl = lane >> 3;                 // 0..7
  const int ce = ((lane & 7) ^ rl) << 3;    // source col elems (XOR swizzle)
  // ds_read addressing (same XOR involution)
  const int swz = (fr & 7) << 3;
  const int colk0 = (fg * 8) ^ swz;
  const int colk1 = (32 + fg * 8) ^ swz;
  const int aOff = (wr * 128 + fr) * 64;
  const int bOff = (wc * 64 + fr) * 64;

  // running source pointers (advance +64 elems per stage of their type)
  const u16* pAlo = xbf + (mBase + w * 8 + rl) * 2048 + ce;
  const u16* pAhi = pAlo + 128 * 2048;
  const u16* pBlo = wbf + (nBase + w * 8 + rl) * 2048 + ce;
  const u16* pBhi = pBlo + 128 * 2048;

  f32x4 acc[8][4];
  const f32x4 zero = {0.f, 0.f, 0.f, 0.f};
#pragma unroll
  for (int mi = 0; mi < 8; ++mi)
#pragma unroll
    for (int nj = 0; nj < 4; ++nj) acc[mi][nj] = zero;

  short8 Aa[2][2], Ab[2][2];   // A mi-pair ping-pong
  short8 Bx[4][2], By[4][2];   // B tile ping-pong (full tile in regs)

#define LGKM(N) asm volatile("s_waitcnt lgkmcnt(" #N ")" ::: "memory")
#define VMC(N)  asm volatile("s_waitcnt vmcnt(" #N ")" ::: "memory")
#define BAR()   __builtin_amdgcn_s_barrier()

  // stage macros: OFF = buffer-parity offset (compile-time), 2 GLL16 each
#define SA_LO(OFF) { GLL16(pAlo, lds + (OFF) + w * 512);                      \
                     GLL16(pAlo + 131072, lds + (OFF) + 4096 + w * 512);      \
                     pAlo += 64; }
#define SA_HI(OFF) { GLL16(pAhi, lds + (OFF) + 8192 + w * 512);               \
                     GLL16(pAhi + 131072, lds + (OFF) + 12288 + w * 512);     \
                     pAhi += 64; }
#define SB_LO(OFF) { GLL16(pBlo, lds + 32768 + (OFF) + w * 512);              \
                     GLL16(pBlo + 131072, lds + 32768 + (OFF) + 4096 + w * 512); \
                     pBlo += 64; }
#define SB_HI(OFF) { GLL16(pBhi, lds + 32768 + (OFF) + 8192 + w * 512);       \
                     GLL16(pBhi + 131072, lds + 32768 + (OFF) + 12288 + w * 512); \
                     pBhi += 64; }

#define RDA(DST, BUF, MI0)                                                    \
  DST[0][0] = *(const short8*)((BUF) + aOff + (MI0) * 1024 + colk0);          \
  DST[0][1] = *(const short8*)((BUF) + aOff + (MI0) * 1024 + colk1);          \
  DST[1][0] = *(const short8*)((BUF) + aOff + ((MI0) + 1) * 1024 + colk0);    \
  DST[1][1] = *(const short8*)((BUF) + aOff + ((MI0) + 1) * 1024 + colk1);

#define RDB(DST, BUF, NJ0)                                                    \
  DST[(NJ0)][0] = *(const short8*)((BUF) + bOff + (NJ0) * 1024 + colk0);      \
  DST[(NJ0)][1] = *(const short8*)((BUF) + bOff + (NJ0) * 1024 + colk1);      \
  DST[(NJ0)+1][0] = *(const short8*)((BUF) + bOff + ((NJ0)+1) * 1024 + colk0);\
  DST[(NJ0)+1][1] = *(const short8*)((BUF) + bOff + ((NJ0)+1) * 1024 + colk1);

#define MFMA16(AV, BV, MI0)                                                   \
  __builtin_amdgcn_s_setprio(1);                                              \
  _Pragma("unroll")                                                           \
  for (int kk = 0; kk < 2; ++kk)                                              \
    _Pragma("unroll")                                                         \
    for (int q = 0; q < 2; ++q)                                               \
      _Pragma("unroll")                                                       \
      for (int nj = 0; nj < 4; ++nj)                                          \
        acc[(MI0) + q][nj] = __builtin_amdgcn_mfma_f32_16x16x32_bf16(         \
            AV[q][kk], BV[nj][kk], acc[(MI0) + q][nj], 0, 0, 0);              \
  __builtin_amdgcn_s_setprio(0);

  // TILE core: stage statements injected (SAL/SAH at p0/p1, SBL/SBH at p2/p3)
#define TILE(P, BC, BN, SAL, SAH, SBL, SBH, VMCP2)                            \
  {                                                                           \
    const u16* Acur = lds + (P) * 16384;                                      \
    const u16* Anxt = lds + (1 - (P)) * 16384;                                \
    const u16* Bnxt = lds + 32768 + (1 - (P)) * 16384;                        \
    /* p0 */                                                                  \
    SAL                                                                       \
    RDA(Ab, Acur, 2)                                                          \
    LGKM(4);                                                                  \
    MFMA16(Aa, BC, 0)                                                         \
    BAR();                                                                    \
    /* p1 */                                                                  \
    SAH                                                                       \
    RDA(Aa, Acur, 4)                                                          \
    LGKM(4);                                                                  \
    MFMA16(Ab, BC, 2)                                                         \
    VMC(4);                                                                   \
    BAR();                                                                    \
    /* p2 */                                                                  \
    SBL                                                                       \
    RDA(Ab, Acur, 6)                                                          \
    RDB(BN, Bnxt, 0)                                                          \
    LGKM(8);                                                                  \
    MFMA16(Aa, BC, 4)                                                         \
    VMCP2;                                                                    \
    BAR();                                                                    \
    /* p3 */                                                                  \
    SBH                                                                       \
    RDA(Aa, Anxt, 0)                                                          \
    RDB(BN, Bnxt, 2)                                                          \
    LGKM(8);                                                                  \
    MFMA16(Ab, BC, 6)                                                         \
    BAR();                                                                    \
  }

  // ---- prologue: stage A0 (off0), B0 (off0), B1 (off 16384); 12 loads
  SA_LO(0) SA_HI(0)
  SB_LO(0) SB_HI(0)
  SB_LO(16384) SB_HI(16384)
  VMC(4);   // retire A0+B0 (8 oldest); B1's 4 stay in flight
  BAR();
  {
    const u16* Bb0 = lds + 32768;
    RDB(Bx, Bb0, 0)
    RDB(Bx, Bb0, 2)
    RDA(Aa, lds, 0)
  }

  // tiles 0..29: A stage dst off = (1-P)*16384, B stage dst off = P*16384
#pragma unroll 1
  for (int tt = 0; tt < 15; ++tt) {
    TILE(0, Bx, By, SA_LO(16384), SA_HI(16384), SB_LO(0), SB_HI(0), VMC(2))
    TILE(1, By, Bx, SA_LO(0), SA_HI(0), SB_LO(16384), SB_HI(16384), VMC(2))
  }

  // ---- tile 30 (P=0): regular A(31) stage; B(32) staged from BmT -> buf0
  {
    const u16* pTlo = BmT + (nBase + w * 8 + rl) * 64 + ce;
    const u16* pThi = pTlo + 128 * 64;
    TILE(0, Bx, By, SA_LO(16384), SA_HI(16384),
         { GLL16(pTlo, lds + 32768 + w * 512);
           GLL16(pTlo + 4096, lds + 32768 + 4096 + w * 512); },
         { GLL16(pThi, lds + 32768 + 8192 + w * 512);
           GLL16(pThi + 4096, lds + 32768 + 12288 + w * 512); },
         VMC(2))
  }
  // ---- tile 31 (P=1): A(32) staged from G -> buf0; no B stage; VMC(0)@p2
  {
    const u16* pGlo = G + (mBase + w * 8 + rl) * 64 + ce;
    const u16* pGhi = pGlo + 128 * 64;
    TILE(1, By, Bx,
         { GLL16(pGlo, lds + w * 512);
           GLL16(pGlo + 4096, lds + 4096 + w * 512); },
         { GLL16(pGhi, lds + 8192 + w * 512);
           GLL16(pGhi + 4096, lds + 12288 + w * 512); },
         { }, { }, VMC(0))
  }

  // ---- tile 32 (LoRA): no stages, no barriers, Bcur = Bx, A in buf0
  {
    const u16* Acur = lds;
    RDA(Ab, Acur, 2)
    LGKM(4);
    MFMA16(Aa, Bx, 0)
    RDA(Aa, Acur, 4)
    LGKM(4);
    MFMA16(Ab, Bx, 2)
    RDA(Ab, Acur, 6)
    LGKM(4);
    MFMA16(Aa, Bx, 4)
    LGKM(0);
    MFMA16(Ab, Bx, 6)
  }

  // ---- epilogue: bias add + store
#pragma unroll
  for (int nj = 0; nj < 4; ++nj) {
    const int n = nBase + wc * 64 + nj * 16 + fr;
    const float bv = bias[n];
#pragma unroll
    for (int mi = 0; mi < 8; ++mi) {
      const int m = mBase + wr * 128 + mi * 16 + fg * 4;
#pragma unroll
      for (int r = 0; r < 4; ++r)
        out[(m + r) * 2048 + n] = acc[mi][nj][r] + bv;
    }
  }
#undef TILE
#undef MFMA16
#undef RDB
#undef RDA
#undef SB_HI
#undef SB_LO
#undef SA_HI
#undef SA_LO
#undef BAR
#undef VMC
#undef LGKM
}

// ---------------------------------------------------------------------------
extern "C" void kernel_launch(void* const* d_in, const int* in_sizes, int n_in,
                              void* d_out, int out_size, void* d_ws, size_t ws_size,
                              hipStream_t stream) {
  const float* x  = (const float*)d_in[0];   // [4,2048,2048]
  const float* Wb = (const float*)d_in[1];   // [2048,2048]
  const float* bb = (const float*)d_in[2];   // [2048]
  const float* Wr = (const float*)d_in[3];   // [8,2048]
  const float* Aw = (const float*)d_in[4];   // [8,8,2048] == [64][2048]
  const float* Bw = (const float*)d_in[5];   // [8,2048,8]

  char* ws = (char*)d_ws;
  u16*   xbf  = (u16*)  (ws + 0);            // 33,554,432 B
  u16*   wbf  = (u16*)  (ws + 33554432);     //  8,388,608 B
  u16*   aabf = (u16*)  (ws + 41943040);     //    262,144 B
  u16*   bmt  = (u16*)  (ws + 42205184);     //    262,144 B
  float* lgt  = (float*)(ws + 42467328);     //    262,144 B
  u16*   G    = (u16*)  (ws + 42729472);     //  1,048,576 B
  // h-partials [8][8192][64] f32 live in d_out; fully consumed by k_topk
  // before k_main overwrites all of d_out. Same-stream ordering.
  float* P   = (float*)d_out;
  float* out = (float*)d_out;

  hipLaunchKernelGGL(k_conv_router, dim3(512),   dim3(512), 0, stream, x, Wr, xbf, lgt);
  hipLaunchKernelGGL(k_convert,     dim3(1064),  dim3(256), 0, stream, Wb, Aw, Bw, wbf, aabf, bmt);
  hipLaunchKernelGGL(k_hgemm,       dim3(32, 8), dim3(256), 0, stream, xbf, aabf, P);
  hipLaunchKernelGGL(k_topk,        dim3(2048),  dim3(256), 0, stream, lgt, P, G);
  hipLaunchKernelGGL(k_main,        dim3(256),   dim3(512), 0, stream, xbf, wbf, G, bmt, bb, out);
}

// Round 11
// 111.099 us; speedup vs baseline: 3.3390x; 1.0424x over previous
//
#include <hip/hip_runtime.h>

typedef unsigned short u16;
typedef __attribute__((ext_vector_type(8))) short short8;
typedef __attribute__((ext_vector_type(4))) float f32x4;

#define GLL16(g, l) __builtin_amdgcn_global_load_lds(                         \
    (const __attribute__((address_space(1))) void*)(g),                        \
    (__attribute__((address_space(3))) void*)(l), 16, 0, 0)

__device__ __forceinline__ u16 f2bf(float f) {
  union { float f; unsigned u; } v; v.f = f;
  unsigned u = v.u;
  return (u16)((u + 0x7FFFu + ((u >> 16) & 1u)) >> 16);  // RNE
}

__device__ __forceinline__ float bf2f(u16 u) {
  union { unsigned u; float f; } v; v.u = ((unsigned)u) << 16;
  return v.f;
}

__device__ __forceinline__ ushort4 cvt4(float4 v) {
  ushort4 o; o.x = f2bf(v.x); o.y = f2bf(v.y); o.z = f2bf(v.z); o.w = f2bf(v.w);
  return o;
}

// ---------------------------------------------------------------------------
// Kernel PRE (fused conv_router + convert): 512 blocks x 512 thr.
//  - x -> bf16 + fp32 router logits (W_router in 64KB LDS), 16 tokens/block
//  - W_base -> bf16, A_w -> bf16, B_w -> BmatT [2048][64] bf16
// All outputs independent; no intra-kernel ordering needed.
// ---------------------------------------------------------------------------
__global__ __launch_bounds__(512) void k_pre(
    const float* __restrict__ x, const float* __restrict__ Wr,
    const float* __restrict__ Wb, const float* __restrict__ Aw,
    const float* __restrict__ Bw,
    u16* __restrict__ xbf, float* __restrict__ logits,
    u16* __restrict__ wbf, u16* __restrict__ aabf, u16* __restrict__ bmt)
{
  __shared__ float wlds[16384];  // 8 x 2048 fp32 = 64 KB
  {
    const float4* src = (const float4*)Wr;
    float4* dst = (float4*)wlds;
    int t = threadIdx.x;
#pragma unroll
    for (int i = 0; i < 8; ++i) dst[t + i * 512] = src[t + i * 512];
  }
  __syncthreads();
  const int wave = threadIdx.x >> 6, lane = threadIdx.x & 63;
  const float4* wv = (const float4*)wlds;
#pragma unroll 1
  for (int s = 0; s < 2; ++s) {
    int tok = blockIdx.x * 16 + wave * 2 + s;
    const float4* xrow = (const float4*)(x + tok * 2048);
    ushort4* orow = (ushort4*)(xbf + tok * 2048);
    float acc[8];
#pragma unroll
    for (int e = 0; e < 8; ++e) acc[e] = 0.f;
#pragma unroll 1
    for (int i = 0; i < 8; ++i) {
      float4 xv = xrow[lane + i * 64];
      orow[lane + i * 64] = cvt4(xv);
#pragma unroll
      for (int e = 0; e < 8; ++e) {
        float4 b = wv[e * 512 + lane + i * 64];
        acc[e] += xv.x * b.x + xv.y * b.y + xv.z * b.z + xv.w * b.w;
      }
    }
#pragma unroll
    for (int e = 0; e < 8; ++e) {
      float v = acc[e];
#pragma unroll
      for (int off = 32; off > 0; off >>= 1) v += __shfl_xor(v, off, 64);
      acc[e] = v;
    }
    if (lane == 0) {
#pragma unroll
      for (int e = 0; e < 8; ++e) logits[tok * 8 + e] = acc[e];
    }
  }
  // ---- weight conversions (262144 threads grid-wide)
  const int tidg = blockIdx.x * 512 + threadIdx.x;
  {
    const float4* src = (const float4*)Wb;   // 1,048,576 float4
    ushort4* dst = (ushort4*)wbf;
#pragma unroll
    for (int i = 0; i < 4; ++i)
      dst[tidg + i * 262144] = cvt4(src[tidg + i * 262144]);
  }
  if (tidg < 32768) {                        // A_w: 32768 float4
    ((ushort4*)aabf)[tidg] = cvt4(((const float4*)Aw)[tidg]);
  }
  if (tidg < 2048) {                         // B_w [8][2048][8] -> bmt [2048][64]
    const int n = tidg;
#pragma unroll
    for (int e = 0; e < 8; ++e) {
      const float4* src = (const float4*)(Bw + e * 16384 + n * 8);
      ushort4* dst = (ushort4*)(bmt + n * 64 + e * 8);
      dst[0] = cvt4(src[0]);
      dst[1] = cvt4(src[1]);
    }
  }
}

// ---------------------------------------------------------------------------
// Kernel C: h partials (bf16). h_all[m][64] = x_bf16 @ A_all^T, split-K=8.
// P stored as u16 bf16 [8][8192][64] (8.4 MB, halves the d_out round-trip).
// ---------------------------------------------------------------------------
__global__ __launch_bounds__(256) void k_hgemm(
    const u16* __restrict__ xbf, const u16* __restrict__ aabf,
    u16* __restrict__ P)
{
  __shared__ u16 As[256 * 64];
  __shared__ u16 Bs[64 * 64];
  int t = threadIdx.x, wave = t >> 6, lane = t & 63;
  int mBase = blockIdx.x * 256;
  int ks = blockIdx.y;
  int fr = lane & 15, fg = lane >> 4;
  int lrow = lane >> 3, lcol = (lane & 7) * 8;
  f32x4 zero = {0.f, 0.f, 0.f, 0.f};
  f32x4 acc[4][4];
#pragma unroll
  for (int i = 0; i < 4; ++i)
#pragma unroll
    for (int j = 0; j < 4; ++j) acc[i][j] = zero;
#pragma unroll 1
  for (int it = 0; it < 4; ++it) {
    int k0 = ks * 256 + it * 64;
    __syncthreads();
#pragma unroll
    for (int cc = 0; cc < 8; ++cc) {
      int c = wave * 8 + cc;
      GLL16(xbf + (mBase + c * 8 + lrow) * 2048 + k0 + lcol, &As[c * 512]);
    }
#pragma unroll
    for (int cc = 0; cc < 2; ++cc) {
      int c = wave * 2 + cc;
      GLL16(aabf + (c * 8 + lrow) * 2048 + k0 + lcol, &Bs[c * 512]);
    }
    __syncthreads();
#pragma unroll
    for (int kk = 0; kk < 2; ++kk) {
      short8 a[4], bfr[4];
#pragma unroll
      for (int i = 0; i < 4; ++i)
        a[i] = *(const short8*)&As[(wave * 64 + i * 16 + fr) * 64 + kk * 32 + fg * 8];
#pragma unroll
      for (int j = 0; j < 4; ++j)
        bfr[j] = *(const short8*)&Bs[(j * 16 + fr) * 64 + kk * 32 + fg * 8];
#pragma unroll
      for (int i = 0; i < 4; ++i)
#pragma unroll
        for (int j = 0; j < 4; ++j)
          acc[i][j] = __builtin_amdgcn_mfma_f32_16x16x32_bf16(a[i], bfr[j], acc[i][j], 0, 0, 0);
    }
  }
#pragma unroll
  for (int i = 0; i < 4; ++i)
#pragma unroll
    for (int j = 0; j < 4; ++j)
#pragma unroll
      for (int r = 0; r < 4; ++r) {
        int m = mBase + wave * 64 + i * 16 + fg * 4 + r;
        int n = j * 16 + fr;
        P[(ks * 8192 + m) * 64 + n] = f2bf(acc[i][j][r]);
      }
}

// ---------------------------------------------------------------------------
// Kernel D: per-token top-2 + softmax gates; reduce bf16 split-K partials;
// emit sparse gate-scaled G[8192][64] bf16.
// ---------------------------------------------------------------------------
__global__ __launch_bounds__(256) void k_topk(
    const float* __restrict__ logits, const u16* __restrict__ P,
    u16* __restrict__ G)
{
  int t = threadIdx.x, wave = t >> 6, lane = t & 63;
  int tok = blockIdx.x * 4 + wave;
  const float* lg = logits + tok * 8;
  float la[8];
#pragma unroll
  for (int e = 0; e < 8; ++e) la[e] = lg[e];
  float v0 = la[0]; int i0 = 0;
#pragma unroll
  for (int e = 1; e < 8; ++e) { if (la[e] > v0) { v0 = la[e]; i0 = e; } }
  float v1 = -3.4e38f; int i1 = 0;
#pragma unroll
  for (int e = 0; e < 8; ++e) { if (e != i0 && la[e] > v1) { v1 = la[e]; i1 = e; } }
  float ex = expf(v1 - v0);
  float inv = 1.f / (1.f + ex);
  float gate0 = inv, gate1 = ex * inv;
  int e = lane >> 3;
  float h = 0.f;
#pragma unroll
  for (int ks = 0; ks < 8; ++ks) h += bf2f(P[(ks * 8192 + tok) * 64 + lane]);
  float g = (e == i0) ? gate0 : ((e == i1) ? gate1 : 0.f);
  G[tok * 64 + lane] = f2bf(2.0f * g * h);  // SCALE = alpha/r = 2
}

// ---------------------------------------------------------------------------
// Kernel E: main GEMM, 256x256, BK=64, R5 read-ahead 4-phase pipeline with
// zero-VALU staging (R10, 69.4us verified). UNCHANGED this round.
// ---------------------------------------------------------------------------
__global__ __launch_bounds__(512, 2) void k_main(
    const u16* __restrict__ xbf, const u16* __restrict__ wbf,
    const u16* __restrict__ G, const u16* __restrict__ BmT,
    const float* __restrict__ bias, float* __restrict__ out)
{
  __shared__ u16 lds[65536];  // A bufs: [0,32768)  B bufs: [32768,65536)
  const int tid = threadIdx.x;
  const int w = tid >> 6, lane = tid & 63;
  const int fr = lane & 15, fg = lane >> 4;
  const int wr = w >> 2, wc = w & 3;

  // XCD-aware swizzle (256 blocks, 256%8==0 -> bijective)
  const int b0 = blockIdx.x;
  const int wg = (b0 & 7) * 32 + (b0 >> 3);
  const int mBase = (wg >> 3) * 256;   // 32 m-tiles
  const int nBase = (wg & 7) * 256;    //  8 n-tiles

  // staging addressing (linear LDS dest; swizzled global source col)
  const int rl = lane >> 3;                 // 0..7
  const int ce = ((lane & 7) ^ rl) << 3;    // source col elems (XOR swizzle)
  // ds_read addressing (same XOR involution)
  const int swz = (fr & 7) << 3;
  const int colk0 = (fg * 8) ^ swz;
  const int colk1 = (32 + fg * 8) ^ swz;
  const int aOff = (wr * 128 + fr) * 64;
  const int bOff = (wc * 64 + fr) * 64;

  // running source pointers (advance +64 elems per stage of their type)
  const u16* pAlo = xbf + (mBase + w * 8 + rl) * 2048 + ce;
  const u16* pAhi = pAlo + 128 * 2048;
  const u16* pBlo = wbf + (nBase + w * 8 + rl) * 2048 + ce;
  const u16* pBhi = pBlo + 128 * 2048;

  f32x4 acc[8][4];
  const f32x4 zero = {0.f, 0.f, 0.f, 0.f};
#pragma unroll
  for (int mi = 0; mi < 8; ++mi)
#pragma unroll
    for (int nj = 0; nj < 4; ++nj) acc[mi][nj] = zero;

  short8 Aa[2][2], Ab[2][2];   // A mi-pair ping-pong
  short8 Bx[4][2], By[4][2];   // B tile ping-pong (full tile in regs)

#define LGKM(N) asm volatile("s_waitcnt lgkmcnt(" #N ")" ::: "memory")
#define VMC(N)  asm volatile("s_waitcnt vmcnt(" #N ")" ::: "memory")
#define BAR()   __builtin_amdgcn_s_barrier()

  // stage macros: OFF = buffer-parity offset (compile-time), 2 GLL16 each
#define SA_LO(OFF) { GLL16(pAlo, lds + (OFF) + w * 512);                      \
                     GLL16(pAlo + 131072, lds + (OFF) + 4096 + w * 512);      \
                     pAlo += 64; }
#define SA_HI(OFF) { GLL16(pAhi, lds + (OFF) + 8192 + w * 512);               \
                     GLL16(pAhi + 131072, lds + (OFF) + 12288 + w * 512);     \
                     pAhi += 64; }
#define SB_LO(OFF) { GLL16(pBlo, lds + 32768 + (OFF) + w * 512);              \
                     GLL16(pBlo + 131072, lds + 32768 + (OFF) + 4096 + w * 512); \
                     pBlo += 64; }
#define SB_HI(OFF) { GLL16(pBhi, lds + 32768 + (OFF) + 8192 + w * 512);       \
                     GLL16(pBhi + 131072, lds + 32768 + (OFF) + 12288 + w * 512); \
                     pBhi += 64; }

#define RDA(DST, BUF, MI0)                                                    \
  DST[0][0] = *(const short8*)((BUF) + aOff + (MI0) * 1024 + colk0);          \
  DST[0][1] = *(const short8*)((BUF) + aOff + (MI0) * 1024 + colk1);          \
  DST[1][0] = *(const short8*)((BUF) + aOff + ((MI0) + 1) * 1024 + colk0);    \
  DST[1][1] = *(const short8*)((BUF) + aOff + ((MI0) + 1) * 1024 + colk1);

#define RDB(DST, BUF, NJ0)                                                    \
  DST[(NJ0)][0] = *(const short8*)((BUF) + bOff + (NJ0) * 1024 + colk0);      \
  DST[(NJ0)][1] = *(const short8*)((BUF) + bOff + (NJ0) * 1024 + colk1);      \
  DST[(NJ0)+1][0] = *(const short8*)((BUF) + bOff + ((NJ0)+1) * 1024 + colk0);\
  DST[(NJ0)+1][1] = *(const short8*)((BUF) + bOff + ((NJ0)+1) * 1024 + colk1);

#define MFMA16(AV, BV, MI0)                                                   \
  __builtin_amdgcn_s_setprio(1);                                              \
  _Pragma("unroll")                                                           \
  for (int kk = 0; kk < 2; ++kk)                                              \
    _Pragma("unroll")                                                         \
    for (int q = 0; q < 2; ++q)                                               \
      _Pragma("unroll")                                                       \
      for (int nj = 0; nj < 4; ++nj)                                          \
        acc[(MI0) + q][nj] = __builtin_amdgcn_mfma_f32_16x16x32_bf16(         \
            AV[q][kk], BV[nj][kk], acc[(MI0) + q][nj], 0, 0, 0);              \
  __builtin_amdgcn_s_setprio(0);

#define TILE(P, BC, BN, SAL, SAH, SBL, SBH, VMCP2)                            \
  {                                                                           \
    const u16* Acur = lds + (P) * 16384;                                      \
    const u16* Anxt = lds + (1 - (P)) * 16384;                                \
    const u16* Bnxt = lds + 32768 + (1 - (P)) * 16384;                        \
    /* p0 */                                                                  \
    SAL                                                                       \
    RDA(Ab, Acur, 2)                                                          \
    LGKM(4);                                                                  \
    MFMA16(Aa, BC, 0)                                                         \
    BAR();                                                                    \
    /* p1 */                                                                  \
    SAH                                                                       \
    RDA(Aa, Acur, 4)                                                          \
    LGKM(4);                                                                  \
    MFMA16(Ab, BC, 2)                                                         \
    VMC(4);                                                                   \
    BAR();                                                                    \
    /* p2 */                                                                  \
    SBL                                                                       \
    RDA(Ab, Acur, 6)                                                          \
    RDB(BN, Bnxt, 0)                                                          \
    LGKM(8);                                                                  \
    MFMA16(Aa, BC, 4)                                                         \
    VMCP2;                                                                    \
    BAR();                                                                    \
    /* p3 */                                                                  \
    SBH                                                                       \
    RDA(Aa, Anxt, 0)                                                          \
    RDB(BN, Bnxt, 2)                                                          \
    LGKM(8);                                                                  \
    MFMA16(Ab, BC, 6)                                                         \
    BAR();                                                                    \
  }

  // ---- prologue: stage A0 (off0), B0 (off0), B1 (off 16384); 12 loads
  SA_LO(0) SA_HI(0)
  SB_LO(0) SB_HI(0)
  SB_LO(16384) SB_HI(16384)
  VMC(4);   // retire A0+B0 (8 oldest); B1's 4 stay in flight
  BAR();
  {
    const u16* Bb0 = lds + 32768;
    RDB(Bx, Bb0, 0)
    RDB(Bx, Bb0, 2)
    RDA(Aa, lds, 0)
  }

  // tiles 0..29: A stage dst off = (1-P)*16384, B stage dst off = P*16384
#pragma unroll 1
  for (int tt = 0; tt < 15; ++tt) {
    TILE(0, Bx, By, SA_LO(16384), SA_HI(16384), SB_LO(0), SB_HI(0), VMC(2))
    TILE(1, By, Bx, SA_LO(0), SA_HI(0), SB_LO(16384), SB_HI(16384), VMC(2))
  }

  // ---- tile 30 (P=0): regular A(31) stage; B(32) staged from BmT -> buf0
  {
    const u16* pTlo = BmT + (nBase + w * 8 + rl) * 64 + ce;
    const u16* pThi = pTlo + 128 * 64;
    TILE(0, Bx, By, SA_LO(16384), SA_HI(16384),
         { GLL16(pTlo, lds + 32768 + w * 512);
           GLL16(pTlo + 4096, lds + 32768 + 4096 + w * 512); },
         { GLL16(pThi, lds + 32768 + 8192 + w * 512);
           GLL16(pThi + 4096, lds + 32768 + 12288 + w * 512); },
         VMC(2))
  }
  // ---- tile 31 (P=1): A(32) staged from G -> buf0; no B stage; VMC(0)@p2
  {
    const u16* pGlo = G + (mBase + w * 8 + rl) * 64 + ce;
    const u16* pGhi = pGlo + 128 * 64;
    TILE(1, By, Bx,
         { GLL16(pGlo, lds + w * 512);
           GLL16(pGlo + 4096, lds + 4096 + w * 512); },
         { GLL16(pGhi, lds + 8192 + w * 512);
           GLL16(pGhi + 4096, lds + 12288 + w * 512); },
         { }, { }, VMC(0))
  }

  // ---- tile 32 (LoRA): no stages, no barriers, Bcur = Bx, A in buf0
  {
    const u16* Acur = lds;
    RDA(Ab, Acur, 2)
    LGKM(4);
    MFMA16(Aa, Bx, 0)
    RDA(Aa, Acur, 4)
    LGKM(4);
    MFMA16(Ab, Bx, 2)
    RDA(Ab, Acur, 6)
    LGKM(4);
    MFMA16(Aa, Bx, 4)
    LGKM(0);
    MFMA16(Ab, Bx, 6)
  }

  // ---- epilogue: bias add + store
#pragma unroll
  for (int nj = 0; nj < 4; ++nj) {
    const int n = nBase + wc * 64 + nj * 16 + fr;
    const float bv = bias[n];
#pragma unroll
    for (int mi = 0; mi < 8; ++mi) {
      const int m = mBase + wr * 128 + mi * 16 + fg * 4;
#pragma unroll
      for (int r = 0; r < 4; ++r)
        out[(m + r) * 2048 + n] = acc[mi][nj][r] + bv;
    }
  }
#undef TILE
#undef MFMA16
#undef RDB
#undef RDA
#undef SB_HI
#undef SB_LO
#undef SA_HI
#undef SA_LO
#undef BAR
#undef VMC
#undef LGKM
}

// ---------------------------------------------------------------------------
extern "C" void kernel_launch(void* const* d_in, const int* in_sizes, int n_in,
                              void* d_out, int out_size, void* d_ws, size_t ws_size,
                              hipStream_t stream) {
  const float* x  = (const float*)d_in[0];   // [4,2048,2048]
  const float* Wb = (const float*)d_in[1];   // [2048,2048]
  const float* bb = (const float*)d_in[2];   // [2048]
  const float* Wr = (const float*)d_in[3];   // [8,2048]
  const float* Aw = (const float*)d_in[4];   // [8,8,2048] == [64][2048]
  const float* Bw = (const float*)d_in[5];   // [8,2048,8]

  char* ws = (char*)d_ws;
  u16*   xbf  = (u16*)  (ws + 0);            // 33,554,432 B
  u16*   wbf  = (u16*)  (ws + 33554432);     //  8,388,608 B
  u16*   aabf = (u16*)  (ws + 41943040);     //    262,144 B
  u16*   bmt  = (u16*)  (ws + 42205184);     //    262,144 B
  float* lgt  = (float*)(ws + 42467328);     //    262,144 B
  u16*   G    = (u16*)  (ws + 42729472);     //  1,048,576 B
  // h-partials [8][8192][64] bf16 (8.4 MB) live in d_out; fully consumed by
  // k_topk before k_main overwrites all of d_out. Same-stream ordering.
  u16*   P   = (u16*)d_out;
  float* out = (float*)d_out;

  hipLaunchKernelGGL(k_pre,   dim3(512),   dim3(512), 0, stream,
                     x, Wr, Wb, Aw, Bw, xbf, lgt, wbf, aabf, bmt);
  hipLaunchKernelGGL(k_hgemm, dim3(32, 8), dim3(256), 0, stream, xbf, aabf, P);
  hipLaunchKernelGGL(k_topk,  dim3(2048),  dim3(256), 0, stream, lgt, P, G);
  hipLaunchKernelGGL(k_main,  dim3(256),   dim3(512), 0, stream,
                     xbf, wbf, G, bmt, bb, out);
}